// Round 4
// baseline (158.979 us; speedup 1.0000x reference)
//
#include <hip/hip_runtime.h>

#define EPSC 1e-10f
#define BDIM 512
#define PDIM 1024
#define NDIM 1024
#define TDIM 32

typedef __attribute__((ext_vector_type(8))) short short8;
typedef __attribute__((ext_vector_type(4))) float f32x4;

static __device__ __forceinline__ short f2bf(float f) {
  unsigned u = __float_as_uint(f);
  unsigned r = (u + 0x7fffu + ((u >> 16) & 1u)) >> 16;
  return (short)r;
}

// ============ merged conversion kernel ============
// blocks [0,256): x fp32 -> bf16 fragment-swizzled  Xsw[((mt*32+kc)*64 + q*16 + r)*8 + e]
// blocks [256,768): w fp32 [k][n] -> bf16 frag-swizzled Wsw[((nt*32+kc)*64 + q*16 + rn)*8 + e]
//                   + per-block sum(w^2) partials -> pwsq[wb]
__global__ __launch_bounds__(256) void conv_kernel(
    const float* __restrict__ X, const float* __restrict__ W1, const float* __restrict__ W2,
    short* __restrict__ Xsw, short* __restrict__ T1, short* __restrict__ T2,
    float* __restrict__ pwsq)
{
  int tid = threadIdx.x;
  if (blockIdx.x < 256) {
    int i = blockIdx.x * 256 + tid;
    int m = i >> 7, c = i & 127;           // c = k/8
    const float* src = X + (size_t)m * 1024 + c * 8;
    float4 v0 = *(const float4*)src;
    float4 v1 = *(const float4*)(src + 4);
    short8 o;
    o[0] = f2bf(v0.x); o[1] = f2bf(v0.y); o[2] = f2bf(v0.z); o[3] = f2bf(v0.w);
    o[4] = f2bf(v1.x); o[5] = f2bf(v1.y); o[6] = f2bf(v1.z); o[7] = f2bf(v1.w);
    // dst: mt=m>>4, kc=c>>2, q=c&3, r=m&15
    *(short8*)(Xsw + ((size_t)((m >> 4) * 32 + (c >> 2)) * 512) + (c & 3) * 128 + (m & 15) * 8) = o;
    return;
  }
  __shared__ float T[64][65];
  __shared__ float red[4];
  int wb = blockIdx.x - 256;
  int z = wb >> 8;
  int w = wb & 255;
  int r0 = (w >> 4) * 64;   // k rows
  int c0 = (w & 15) * 64;   // n cols
  const float* src = z ? W2 : W1;
  short* dst = z ? T2 : T1;
  float wsq = 0.0f;
#pragma unroll
  for (int i = 0; i < 4; ++i) {
    int row = (tid >> 4) + i * 16;
    int col = (tid & 15) << 2;
    float4 v = *(const float4*)(src + (size_t)(r0 + row) * NDIM + c0 + col);
    T[row][col + 0] = v.x; T[row][col + 1] = v.y; T[row][col + 2] = v.z; T[row][col + 3] = v.w;
    wsq = fmaf(v.x, v.x, wsq); wsq = fmaf(v.y, v.y, wsq);
    wsq = fmaf(v.z, v.z, wsq); wsq = fmaf(v.w, v.w, wsq);
  }
  __syncthreads();
  int nl = tid >> 2;              // 0..63 (col within tile)
  int kb = (tid & 3) << 4;        // 0,16,32,48
  int ng = c0 + nl;
  int nt = ng >> 4, rn = ng & 15;
#pragma unroll
  for (int h = 0; h < 2; ++h) {
    int kg = r0 + kb + 8 * h;
    int kc = kg >> 5, q = (kg >> 3) & 3;
    short8 o;
#pragma unroll
    for (int e = 0; e < 8; ++e) o[e] = f2bf(T[kb + 8 * h + e][nl]);
    *(short8*)(dst + ((size_t)(nt * 32 + kc) * 512) + q * 128 + rn * 8) = o;
  }
#pragma unroll
  for (int d = 32; d >= 1; d >>= 1) wsq += __shfl_xor(wsq, d);
  if ((tid & 63) == 0) red[tid >> 6] = wsq;
  __syncthreads();
  if (tid == 0) pwsq[wb] = red[0] + red[1] + red[2] + red[3];
}

// ============ gemm1: a = relu(x@w_enc + b); Absw (frag-swizzled bf16); U[n][b] ============
// 4 waves/block, wave tile 16x16, block tile 32x32, grid (32,16)=512 blocks
__global__ __launch_bounds__(256) void gemm1_mfma(
    const short* __restrict__ Xsw, const short* __restrict__ Wsw,
    const float* __restrict__ bias, const float* __restrict__ centers,
    short* __restrict__ Absw, float* __restrict__ U, int* __restrict__ ticket)
{
  __shared__ float T2s[32][36];
  int tid = threadIdx.x;
  if (blockIdx.x == 0 && blockIdx.y == 0 && tid == 0) *ticket = 0;
  int lane = tid & 63, wid = tid >> 6;
  int wy = wid >> 1, wx = wid & 1;
  int mt = blockIdx.y * 2 + wy;
  int nt = blockIdx.x * 2 + wx;
  const short* ap = Xsw + (size_t)mt * 16384 + lane * 8;
  const short* bp = Wsw + (size_t)nt * 16384 + lane * 8;
  f32x4 acc = {0.f, 0.f, 0.f, 0.f};
#pragma unroll 8
  for (int kc = 0; kc < 32; ++kc) {
    short8 a = *(const short8*)(ap + kc * 512);
    short8 b = *(const short8*)(bp + kc * 512);
    acc = __builtin_amdgcn_mfma_f32_16x16x32_bf16(a, b, acc, 0, 0, 0);
  }
  int q = lane >> 4, r = lane & 15;
  int nn = nt * 16 + r;
  float bi = bias[nn];
  float c0 = centers[0];
  float invw = 1.0f / (centers[1] - centers[0]);
  // Absw dest (fixed per thread except rm): kc2 = nn>>5, q2=(nn>>3)&3, e2=nn&7
  short* abase = Absw + ((size_t)(mt * 32 + (nn >> 5)) * 512) + ((nn >> 3) & 3) * 128 + (nn & 7);
#pragma unroll
  for (int rr = 0; rr < 4; ++rr) {
    int rm = q * 4 + rr;                 // mm & 15
    float a = fmaxf(acc[rr] + bi, 0.0f);
    abase[rm * 8] = f2bf(a);
    T2s[wx * 16 + r][wy * 16 + rm] = (2.0f / (1.0f + __expf(-a)) - 1.0f - c0) * invw;
  }
  __syncthreads();
  int row = tid >> 3;            // n-local 0..31
  int col4 = (tid & 7) << 2;     // b-local
  float4 uv = make_float4(T2s[row][col4], T2s[row][col4 + 1], T2s[row][col4 + 2], T2s[row][col4 + 3]);
  *(float4*)(U + (size_t)(blockIdx.x * 32 + row) * BDIM + blockIdx.y * 32 + col4) = uv;
}

// ============ gemm2: x_hat = a@w_dec + b_dec; per-block recon partials ============
__global__ __launch_bounds__(256) void gemm2_mfma(
    const short* __restrict__ Absw, const short* __restrict__ Wdsw,
    const float* __restrict__ bias, const float* __restrict__ X,
    float* __restrict__ out, float* __restrict__ precon)
{
  __shared__ float red[4];
  int tid = threadIdx.x;
  int lane = tid & 63, wid = tid >> 6;
  int wy = wid >> 1, wx = wid & 1;
  int mt = blockIdx.y * 2 + wy;
  int nt = blockIdx.x * 2 + wx;
  const short* ap = Absw + (size_t)mt * 16384 + lane * 8;
  const short* bp = Wdsw + (size_t)nt * 16384 + lane * 8;
  f32x4 acc = {0.f, 0.f, 0.f, 0.f};
#pragma unroll 8
  for (int kc = 0; kc < 32; ++kc) {
    short8 a = *(const short8*)(ap + kc * 512);
    short8 b = *(const short8*)(bp + kc * 512);
    acc = __builtin_amdgcn_mfma_f32_16x16x32_bf16(a, b, acc, 0, 0, 0);
  }
  int q = lane >> 4, r = lane & 15;
  int nn = nt * 16 + r;
  float bi = bias[nn];
  float local = 0.0f;
#pragma unroll
  for (int rr = 0; rr < 4; ++rr) {
    int mm = mt * 16 + q * 4 + rr;
    float xh = acc[rr] + bi;
    out[(size_t)mm * PDIM + nn] = xh;
    float d = xh - X[(size_t)mm * PDIM + nn];
    local = fmaf(d, d, local);
  }
#pragma unroll
  for (int d = 32; d >= 1; d >>= 1) local += __shfl_xor(local, d);
  if ((tid & 63) == 0) red[tid >> 6] = local;
  __syncthreads();
  if (tid == 0) precon[blockIdx.y * 32 + blockIdx.x] = red[0] + red[1] + red[2] + red[3];
}

// ============ MLE (15 steps) + entropy + fused finalize ============
__global__ __launch_bounds__(64) void mle_kernel(
    const float* __restrict__ U, const float* __restrict__ thetas,
    float* __restrict__ ent_out, const float* __restrict__ precon,
    const float* __restrict__ pwsq, int* __restrict__ ticket, float* __restrict__ out)
{
  int n = blockIdx.x;
  int lane = threadIdx.x;
  __shared__ float s_s[128 * 34];   // 2 slices per lane, stride 34 (2-way banking = free)
  __shared__ int tick_s;

  float f_reg[8];
  int j_reg[8];
#pragma unroll
  for (int i = 0; i < 8; i++) {
    float u = U[(size_t)n * BDIM + lane + i * 64];
    int j = (int)u;
    if (j > TDIM - 2) j = TDIM - 2;
    if (j < 0) j = 0;
    f_reg[i] = u - (float)j;
    j_reg[i] = j;
  }
  float th = (lane < TDIM) ? thetas[(size_t)n * TDIM + lane] : 0.0f;

  int base0 = lane * 34;
  int base1 = (lane + 64) * 34;
  int h = lane >> 5, t = lane & 31;
  float pv = 0.0f;

  for (int step = 0; step < 15; ++step) {
    float tv = __shfl(th, lane & 31);
    float mx = tv;
#pragma unroll
    for (int d = 16; d >= 1; d >>= 1) mx = fmaxf(mx, __shfl_xor(mx, d));
    float e = __expf(tv - mx);
    float se = e;
#pragma unroll
    for (int d = 16; d >= 1; d >>= 1) se += __shfl_xor(se, d);
    pv = e / se;            // all lanes hold pi[lane&31]
    // zero own 2 slices (aligned float2)
#pragma unroll
    for (int i = 0; i < 17; i++) {
      *(float2*)&s_s[base0 + 2 * i] = make_float2(0.f, 0.f);
      *(float2*)&s_s[base1 + 2 * i] = make_float2(0.f, 0.f);
    }
    float S_local = 0.0f;
#pragma unroll
    for (int i = 0; i < 8; i++) {
      int j = j_reg[i];
      float f = f_reg[i];
      float pj  = __shfl(pv, j);
      float pj1 = __shfl(pv, j + 1);
      float p = (1.0f - f) * pj + f * pj1;
      float r = 1.0f / (p + EPSC);
      S_local = fmaf(p, r, S_local);
      float* sp = &s_s[(i < 4 ? base0 : base1) + j];
      sp[0] += (1.0f - f) * r;
      sp[1] += f * r;
    }
    __syncthreads();
    float S = S_local;
#pragma unroll
    for (int d = 32; d >= 1; d >>= 1) S += __shfl_xor(S, d);
    float colsum = 0.0f;
#pragma unroll 8
    for (int L = 0; L < 64; ++L) colsum += s_s[(h * 64 + L) * 34 + t];
    colsum += __shfl_xor(colsum, 32);
    if (lane < TDIM) th += 0.01f * pv * (colsum - S);
    __syncthreads();
  }

  // final softmax + entropy
  float tv = __shfl(th, lane & 31);
  float mx = tv;
#pragma unroll
  for (int d = 16; d >= 1; d >>= 1) mx = fmaxf(mx, __shfl_xor(mx, d));
  float e = __expf(tv - mx);
  float se = e;
#pragma unroll
  for (int d = 16; d >= 1; d >>= 1) se += __shfl_xor(se, d);
  pv = e / se;
  float ent_local = 0.0f;
#pragma unroll
  for (int i = 0; i < 8; i++) {
    int j = j_reg[i];
    float f = f_reg[i];
    float p = (1.0f - f) * __shfl(pv, j) + f * __shfl(pv, j + 1);
    ent_local = fmaf(p, __logf(p + EPSC), ent_local);
  }
  float E = ent_local;
#pragma unroll
  for (int d = 32; d >= 1; d >>= 1) E += __shfl_xor(E, d);
  if (lane == 0) ent_out[n] = -E;

  // ---- last-block finalize ----
  __threadfence();
  if (lane == 0) tick_s = atomicAdd(ticket, 1);
  __syncthreads();
  if (tick_s == NDIM - 1) {
    __threadfence();
    const volatile float* ev = (const volatile float*)ent_out;
    float acc = 0.0f;
#pragma unroll
    for (int i = 0; i < 16; i++) acc += 0.01f * ev[lane + i * 64];
#pragma unroll
    for (int i = 0; i < 8; i++) acc += (0.5f / (float)BDIM) * precon[lane + i * 64];
#pragma unroll
    for (int i = 0; i < 8; i++) acc += 0.00025f * pwsq[lane + i * 64];
#pragma unroll
    for (int d = 32; d >= 1; d >>= 1) acc += __shfl_xor(acc, d);
    if (lane == 0) out[(size_t)BDIM * PDIM + NDIM] = acc;
  }
}

extern "C" void kernel_launch(void* const* d_in, const int* in_sizes, int n_in,
                              void* d_out, int out_size, void* d_ws, size_t ws_size,
                              hipStream_t stream) {
  (void)in_sizes; (void)n_in; (void)out_size; (void)ws_size;
  const float* x       = (const float*)d_in[0];
  const float* w_enc   = (const float*)d_in[1];
  const float* b_enc   = (const float*)d_in[2];
  const float* w_dec   = (const float*)d_in[3];
  const float* b_dec   = (const float*)d_in[4];
  const float* thetas  = (const float*)d_in[5];
  const float* centers = (const float*)d_in[6];
  float* out = (float*)d_out;

  char* ws = (char*)d_ws;
  short* Xsw    = (short*)(ws);                       // 1 MB
  short* Wsw    = (short*)(ws + (1 << 20));           // 2 MB
  short* Wdsw   = (short*)(ws + (3 << 20));           // 2 MB
  short* Absw   = (short*)(ws + (5 << 20));           // 1 MB
  float* U      = (float*)(ws + (6 << 20));           // 2 MB
  float* precon = (float*)(ws + (8 << 20));           // 2 KB
  float* pwsq   = (float*)(ws + (8 << 20) + 4096);    // 2 KB
  int*   ticket = (int*)(ws + (8 << 20) + 8192);      // 4 B
  float* ent_out = out + (size_t)BDIM * PDIM;

  hipLaunchKernelGGL(conv_kernel, dim3(768), dim3(256), 0, stream,
                     x, w_enc, w_dec, Xsw, Wsw, Wdsw, pwsq);
  hipLaunchKernelGGL(gemm1_mfma, dim3(32, 16), dim3(256), 0, stream,
                     Xsw, Wsw, b_enc, centers, Absw, U, ticket);
  hipLaunchKernelGGL(gemm2_mfma, dim3(32, 16), dim3(256), 0, stream,
                     Absw, Wdsw, b_dec, x, out, precon);
  hipLaunchKernelGGL(mle_kernel, dim3(NDIM), dim3(64), 0, stream,
                     U, thetas, ent_out, precon, pwsq, ticket, out);
}